// Round 7
// baseline (324.130 us; speedup 1.0000x reference)
//
#include <hip/hip_runtime.h>
#include <hip/hip_bf16.h>
#include <stdint.h>

// Problem constants
#define BATCH 64
#define IN_CAPS 512          // In (input capsules)
#define NCAP 16              // num_capsule
#define DCAP 64              // dim_capsule
#define GN (NCAP * DCAP)     // 1024
#define GM (BATCH * IN_CAPS) // 32768
#define GK 768               // input feature dim (K)

typedef __bf16 bf16;
typedef __attribute__((ext_vector_type(8))) __bf16 bf16x8;
typedef __attribute__((ext_vector_type(4))) float f32x4;

// async global->LDS 16B copy (wave-uniform LDS base + lane*16)
__device__ inline void async16(const bf16* g, bf16* l) {
    __builtin_amdgcn_global_load_lds(
        (__attribute__((address_space(1))) void*)g,
        (__attribute__((address_space(3))) void*)l, 16, 0, 0);
}

// ---------------------------------------------------------------------------
// Kernel 1 (NEW): fused prep.  Blocks [0,1024): X->bf16 convert + per-block
// row-sum partial -> XSP[block][768] (plain store, NO atomics/zeroing).
// Blocks [1024,1792): W transpose tiles (768 tiles of 32x32).
// Replaces the separate k_transW + k_convX2 launches (-1 launch, -atomics).
// ---------------------------------------------------------------------------
__global__ __launch_bounds__(256) void k_prep(const float* __restrict__ X,
                                              bf16* __restrict__ Xb,
                                              float* __restrict__ XSP,
                                              const float* __restrict__ W,
                                              bf16* __restrict__ Wt) {
    __shared__ float ls[GK];        // 3 KiB (convX part)
    __shared__ bf16 tsh[32][33];    // 2.1 KiB (transW part)
    const int tid = threadIdx.x;

    if (blockIdx.x < 1024) {
        // ---- convX part: 32 rows of X, register row-sum accumulation ----
        ls[tid] = 0.f; ls[tid + 256] = 0.f; ls[tid + 512] = 0.f;
        __syncthreads();
        const size_t base = (size_t)blockIdx.x * (32 * GK);
        float acc[3][8] = {};  // k-phase cycles with period 3 (r*2048 % 768)
#pragma unroll
        for (int r = 0; r < 12; ++r) {
            const int off = r * 2048 + tid * 8;
            const f32x4 a0 = *(const f32x4*)(X + base + off);
            const f32x4 a1 = *(const f32x4*)(X + base + off + 4);
            bf16x8 o;
            o[0] = (bf16)a0[0]; o[1] = (bf16)a0[1]; o[2] = (bf16)a0[2]; o[3] = (bf16)a0[3];
            o[4] = (bf16)a1[0]; o[5] = (bf16)a1[1]; o[6] = (bf16)a1[2]; o[7] = (bf16)a1[3];
            *(bf16x8*)(Xb + base + off) = o;
            const int g = r % 3;  // compile-time within the unrolled body
            acc[g][0] += a0[0]; acc[g][1] += a0[1];
            acc[g][2] += a0[2]; acc[g][3] += a0[3];
            acc[g][4] += a1[0]; acc[g][5] += a1[1];
            acc[g][6] += a1[2]; acc[g][7] += a1[3];
        }
        // one-time LDS merge (24 atomics/thread, off the streaming path)
#pragma unroll
        for (int g = 0; g < 3; ++g) {
            const int cg = (g == 1) ? 512 : (g == 2) ? 256 : 0;
            const int kb = (tid * 8 + cg) % GK;
#pragma unroll
            for (int j = 0; j < 8; ++j) atomicAdd(&ls[kb + j], acc[g][j]);
        }
        __syncthreads();
        // plain store of the per-block partial (no zeroing, no global atomics)
        float* P = XSP + (size_t)blockIdx.x * GK;
        P[tid] = ls[tid]; P[tid + 256] = ls[tid + 256]; P[tid + 512] = ls[tid + 512];
    } else {
        // ---- transW part: tile t of W [768][1024] -> Wt [1024][768] bf16 ----
        const int t = blockIdx.x - 1024;       // 0..767
        const int k0 = (t % 24) * 32;          // 24 k-tiles
        const int n0 = (t / 24) * 32;          // 32 n-tiles
        const int tx = tid & 31, ty = tid >> 5; // 32 x 8
#pragma unroll
        for (int r = 0; r < 4; ++r)
            tsh[ty + r * 8][tx] = (bf16)W[(size_t)(k0 + ty + r * 8) * GN + n0 + tx];
        __syncthreads();
#pragma unroll
        for (int r = 0; r < 4; ++r)
            Wt[(size_t)(n0 + ty + r * 8) * GK + k0 + tx] = tsh[tx][ty + r * 8];
    }
}

// ---------------------------------------------------------------------------
// Kernel 2 (fallback tiers only): X -> bf16, no row-sums.
// ---------------------------------------------------------------------------
__global__ __launch_bounds__(256) void k_convX(const float* __restrict__ X,
                                               bf16* __restrict__ Xb) {
    const size_t i = ((size_t)blockIdx.x * 256 + threadIdx.x) * 8;
    const f32x4 a = *(const f32x4*)(X + i);
    const f32x4 b = *(const f32x4*)(X + i + 4);
    bf16x8 r;
    r[0] = (bf16)a[0]; r[1] = (bf16)a[1]; r[2] = (bf16)a[2]; r[3] = (bf16)a[3];
    r[4] = (bf16)b[0]; r[5] = (bf16)b[1]; r[6] = (bf16)b[2]; r[7] = (bf16)b[3];
    *(bf16x8*)(Xb + i) = r;
}

// ---------------------------------------------------------------------------
// Kernel 2b (fallback tiers only): W transpose.
// ---------------------------------------------------------------------------
__global__ void k_transW(const float* __restrict__ W, bf16* __restrict__ Wt) {
    __shared__ bf16 t[32][33];
    const int k0 = blockIdx.x * 32;
    const int n0 = blockIdx.y * 32;
    const int tx = threadIdx.x, ty = threadIdx.y;
#pragma unroll
    for (int r = 0; r < 4; ++r)
        t[ty + r * 8][tx] = (bf16)W[(size_t)(k0 + ty + r * 8) * GN + n0 + tx];
    __syncthreads();
#pragma unroll
    for (int r = 0; r < 4; ++r)
        Wt[(size_t)(n0 + ty + r * 8) * GK + k0 + tx] = t[tx][ty + r * 8];
}

// ---------------------------------------------------------------------------
// Kernel 3: out1 = squash((1/16) * xsum . W) — now sums the 16 XSP partials
// per b (coalesced, L2-hot) instead of reading an atomically-built XS.
// ---------------------------------------------------------------------------
__global__ __launch_bounds__(256) void k_out1(const float* __restrict__ XSP,
                                              const float* __restrict__ W,
                                              float* __restrict__ O1) {
    __shared__ float xs[4][GK];      // 12 KiB
    __shared__ float red[4][4][64];  // 4 KiB [bb][kq][k]
    const int cap = blockIdx.x & 15;
    const int bg = blockIdx.x >> 4;
    const int tid = threadIdx.x;
    const int k = tid & 63, kq = tid >> 6;
#pragma unroll
    for (int bb = 0; bb < 4; ++bb) {
        const float* P = XSP + (size_t)(bg * 4 + bb) * 16 * GK;
        float s0 = 0.f, s1 = 0.f, s2 = 0.f;
#pragma unroll
        for (int s = 0; s < 16; ++s) {
            s0 += P[s * GK + tid];
            s1 += P[s * GK + tid + 256];
            s2 += P[s * GK + tid + 512];
        }
        xs[bb][tid] = s0; xs[bb][tid + 256] = s1; xs[bb][tid + 512] = s2;
    }
    __syncthreads();
    float acc4[4] = {0.f, 0.f, 0.f, 0.f};
    const float* wp = W + (size_t)(kq * 192) * GN + cap * 64 + k;
#pragma unroll 4
    for (int kk = 0; kk < 192; ++kk) {
        const float w = wp[(size_t)kk * GN];
        const int kx = kq * 192 + kk;
        acc4[0] += xs[0][kx] * w;
        acc4[1] += xs[1][kx] * w;
        acc4[2] += xs[2][kx] * w;
        acc4[3] += xs[3][kx] * w;
    }
#pragma unroll
    for (int bb = 0; bb < 4; ++bb) red[bb][kq][k] = acc4[bb];
    __syncthreads();
    if (tid < 64) {
#pragma unroll
        for (int bb = 0; bb < 4; ++bb) {
            float s = (red[bb][0][tid] + red[bb][1][tid] +
                       red[bb][2][tid] + red[bb][3][tid]) * 0.0625f;
            float ss = s * s;
#pragma unroll
            for (int off = 32; off >= 1; off >>= 1) ss += __shfl_xor(ss, off);
            O1[((size_t)(bg * 4 + bb) * NCAP + cap) * DCAP + tid] =
                s * rsqrtf(ss + 1e-7f);
        }
    }
}

// ---------------------------------------------------------------------------
// Kernel 4: MFMA GEMM — round-0 validated staging (address-ordered lanes;
// DO NOT trade intra-wave address order for LDS conflict purity — rounds 3-4
// lost 40 µs that way).  ROUND-7 change: XCD-bijective block swizzle (T1):
// 1-D grid 2048 (2048%8==0 -> bijective); XCD x gets m-tiles [32x,32x+32),
// and the 8 n-blocks of each m-tile run consecutively on the SAME XCD ->
// A-tile stays L2-hot for its 8 consumers.
// Epilogue: U store + BL1 = <out1, u_j> from fp32 accumulators (validated).
// ---------------------------------------------------------------------------
__global__ __launch_bounds__(256) void k_gemm_async(const bf16* __restrict__ Xb,
                                                    const bf16* __restrict__ Wt,
                                                    const float* __restrict__ O1,
                                                    bf16* __restrict__ U,
                                                    float* __restrict__ BL) {
    __shared__ bf16 sA[128 * 32];
    __shared__ bf16 sB[128 * 32];

    const int tid = threadIdx.x;
    const int lane = tid & 63;
    const int wave = tid >> 6;
    const int wm = wave >> 1, wn = wave & 1;
    // XCD swizzle: bid%8 = XCD; give XCD x a contiguous m-range, n fastest.
    const int bid = blockIdx.x;
    const int swz = (bid & 7) * 256 + (bid >> 3);
    const int m0 = (swz >> 3) * 128;
    const int n0 = (swz & 7) * 128;

    const int c0 = wave * 2, c1 = wave * 2 + 1;
    const int rl = lane >> 2, cl = (lane & 3) * 8;
    const bf16* gA0 = Xb + (size_t)(m0 + c0 * 16 + rl) * GK + cl;
    const bf16* gA1 = Xb + (size_t)(m0 + c1 * 16 + rl) * GK + cl;
    const bf16* gB0 = Wt + (size_t)(n0 + c0 * 16 + rl) * GK + cl;
    const bf16* gB1 = Wt + (size_t)(n0 + c1 * 16 + rl) * GK + cl;
    bf16* lA0 = sA + c0 * 512;
    bf16* lA1 = sA + c1 * 512;
    bf16* lB0 = sB + c0 * 512;
    bf16* lB1 = sB + c1 * 512;

    f32x4 acc[4][4] = {};
    const int fr = lane & 15;
    const int fq = lane >> 4;

    for (int kt = 0; kt < GK / 32; ++kt) {
        __syncthreads();
        async16(gA0, lA0);
        async16(gA1, lA1);
        async16(gB0, lB0);
        async16(gB1, lB1);
        gA0 += 32; gA1 += 32; gB0 += 32; gB1 += 32;
        __syncthreads();

        bf16x8 af[4], bfr[4];
#pragma unroll
        for (int mi = 0; mi < 4; ++mi)
            af[mi] = *(const bf16x8*)(sA + (wm * 64 + mi * 16 + fr) * 32 + fq * 8);
#pragma unroll
        for (int ni = 0; ni < 4; ++ni)
            bfr[ni] = *(const bf16x8*)(sB + (wn * 64 + ni * 16 + fr) * 32 + fq * 8);
#pragma unroll
        for (int mi = 0; mi < 4; ++mi)
#pragma unroll
            for (int ni = 0; ni < 4; ++ni)
                acc[mi][ni] = __builtin_amdgcn_mfma_f32_16x16x32_bf16(
                    af[mi], bfr[ni], acc[mi][ni], 0, 0, 0);
    }

    // --- epilogue: U store (validated mapping) ---
#pragma unroll
    for (int mi = 0; mi < 4; ++mi) {
#pragma unroll
        for (int ni = 0; ni < 4; ++ni) {
#pragma unroll
            for (int r = 0; r < 4; ++r) {
                const int m = m0 + wm * 64 + mi * 16 + fq * 4 + r;
                const int n = n0 + wn * 64 + ni * 16 + fr;
                const int bb = m >> 9, j = m & 511;
                const int ci = n >> 6, k = n & 63;
                U[(((size_t)(bb * NCAP + ci)) * IN_CAPS + j) * DCAP + k] =
                    (bf16)acc[mi][ni][r];
            }
        }
    }

    // --- epilogue: BL1[b,cap,j] = <out1[b,cap,:], u[b,cap,j,:]> (validated) ---
    if (O1 != nullptr) {
        const int b = m0 >> 9;
        const int cap = (n0 >> 6) + wn;
        float o1v[4];
#pragma unroll
        for (int ni = 0; ni < 4; ++ni)
            o1v[ni] = O1[(size_t)b * GN + n0 + wn * 64 + ni * 16 + fr];
#pragma unroll
        for (int mi = 0; mi < 4; ++mi) {
#pragma unroll
            for (int r = 0; r < 4; ++r) {
                float p = o1v[0] * acc[mi][0][r] + o1v[1] * acc[mi][1][r] +
                          o1v[2] * acc[mi][2][r] + o1v[3] * acc[mi][3][r];
                p += __shfl_xor(p, 1);
                p += __shfl_xor(p, 2);
                p += __shfl_xor(p, 4);
                p += __shfl_xor(p, 8);
                if (fr == 0) {
                    const int j = (m0 & 511) + wm * 64 + mi * 16 + fq * 4 + r;
                    BL[((size_t)(b * NCAP + cap)) * IN_CAPS + j] = p;
                }
            }
        }
    }
}

// ---------------------------------------------------------------------------
// Kernel 4b: fallback GEMM (validated, inline conversion).
// ---------------------------------------------------------------------------
__global__ __launch_bounds__(256) void k_gemm_inline(const float* __restrict__ X,
                                                     const bf16* __restrict__ Wt,
                                                     bf16* __restrict__ U) {
    __shared__ bf16 sA[128 * 32];
    __shared__ bf16 sB[128 * 32];
    const int tid = threadIdx.x;
    const int lane = tid & 63;
    const int wave = tid >> 6;
    const int wm = wave >> 1, wn = wave & 1;
    const int m0 = blockIdx.x * 128;
    const int n0 = blockIdx.y * 128;
    const int srow = tid >> 2;
    const int scol = (tid & 3) * 8;
    f32x4 acc[4][4] = {};
    const int fr = lane & 15;
    const int fq = lane >> 4;
    for (int kt = 0; kt < GK / 32; ++kt) {
        const int kb = kt * 32;
        bf16x8 a0, a1, b0, b1;
        {
            const float* p = X + (size_t)(m0 + srow) * GK + kb + scol;
            const f32x4 x0 = *(const f32x4*)p, x1 = *(const f32x4*)(p + 4);
            const float* q = X + (size_t)(m0 + srow + 64) * GK + kb + scol;
            const f32x4 y0 = *(const f32x4*)q, y1 = *(const f32x4*)(q + 4);
#pragma unroll
            for (int c = 0; c < 4; ++c) {
                a0[c] = (bf16)x0[c]; a0[c + 4] = (bf16)x1[c];
                a1[c] = (bf16)y0[c]; a1[c + 4] = (bf16)y1[c];
            }
        }
        b0 = *(const bf16x8*)(Wt + (size_t)(n0 + srow) * GK + kb + scol);
        b1 = *(const bf16x8*)(Wt + (size_t)(n0 + srow + 64) * GK + kb + scol);
        __syncthreads();
        *(bf16x8*)(sA + srow * 32 + scol) = a0;
        *(bf16x8*)(sA + (srow + 64) * 32 + scol) = a1;
        *(bf16x8*)(sB + srow * 32 + scol) = b0;
        *(bf16x8*)(sB + (srow + 64) * 32 + scol) = b1;
        __syncthreads();
        bf16x8 af[4], bfr[4];
#pragma unroll
        for (int mi = 0; mi < 4; ++mi)
            af[mi] = *(const bf16x8*)(sA + (wm * 64 + mi * 16 + fr) * 32 + fq * 8);
#pragma unroll
        for (int ni = 0; ni < 4; ++ni)
            bfr[ni] = *(const bf16x8*)(sB + (wn * 64 + ni * 16 + fr) * 32 + fq * 8);
#pragma unroll
        for (int mi = 0; mi < 4; ++mi)
#pragma unroll
            for (int ni = 0; ni < 4; ++ni)
                acc[mi][ni] = __builtin_amdgcn_mfma_f32_16x16x32_bf16(
                    af[mi], bfr[ni], acc[mi][ni], 0, 0, 0);
    }
#pragma unroll
    for (int mi = 0; mi < 4; ++mi) {
#pragma unroll
        for (int ni = 0; ni < 4; ++ni) {
#pragma unroll
            for (int r = 0; r < 4; ++r) {
                const int m = m0 + wm * 64 + mi * 16 + fq * 4 + r;
                const int n = n0 + wn * 64 + ni * 16 + fr;
                const int bb = m >> 9, j = m & 511;
                const int ci = n >> 6, k = n & 63;
                U[(((size_t)(bb * NCAP + ci)) * IN_CAPS + j) * DCAP + k] =
                    (bf16)acc[mi][ni][r];
            }
        }
    }
}

// ---------------------------------------------------------------------------
// Kernel 5 (NEW): routing iteration 2, register-staged.  Phase A sweeps U
// ONCE into ur[16] (64 VGPR, all indices compile-time -> registers, NOT
// scratch: verify WRITE_SIZE stays ~2 MiB); phase B reads registers.
// Writes BL2 to a SEPARATE buffer (dead Xb) -> route2 reads it; removes the
// latent same-buffer BL race entirely.  No launch-bounds squeeze (the coop
// attempt's (256,4) caused a 96 MB scratch spill).
// ---------------------------------------------------------------------------
__global__ void k_route1r(const bf16* __restrict__ U,
                          const float* __restrict__ BLin,
                          float* __restrict__ BLout) {
    __shared__ float sc[IN_CAPS];  // 2 KiB
    __shared__ float red2[4][64];  // 1 KiB
    __shared__ float sout[64];     // 256 B
    const int bi = blockIdx.x;
    const int b = bi >> 4, cap = bi & 15;
    const int tid = threadIdx.x;
    const int lane = tid & 63;
    const int wave = tid >> 6;
    const int g = tid & 7;
    const int jr = tid >> 3;
    const size_t ubase = (size_t)bi * IN_CAPS * DCAP;

    // softmax over caps (2-pass, low live registers)
#pragma unroll
    for (int h = 0; h < 2; ++h) {
        const int j = tid + h * 256;
        const float* p = BLin + (size_t)b * NCAP * IN_CAPS + j;
        float mx = -1e30f;
#pragma unroll
        for (int i = 0; i < 16; ++i) mx = fmaxf(mx, p[(size_t)i * IN_CAPS]);
        float s = 0.f;
#pragma unroll
        for (int i = 0; i < 16; ++i) s += __expf(p[(size_t)i * IN_CAPS] - mx);
        sc[j] = __expf(p[(size_t)cap * IN_CAPS] - mx) / s;
    }
    __syncthreads();

    // phase A: single U sweep -> registers + weighted sum
    bf16x8 ur[16];
    float acc[8] = {};
#pragma unroll
    for (int it = 0; it < 16; ++it) {
        ur[it] = *(const bf16x8*)(U + ubase + (size_t)it * 2048 + tid * 8);
        const float cv = sc[it * 32 + jr];
#pragma unroll
        for (int c = 0; c < 8; ++c) acc[c] += cv * (float)ur[it][c];
    }
#pragma unroll
    for (int c = 0; c < 8; ++c) {
        acc[c] += __shfl_xor(acc[c], 8);
        acc[c] += __shfl_xor(acc[c], 16);
        acc[c] += __shfl_xor(acc[c], 32);
    }
    if ((lane >> 3) == 0) {
#pragma unroll
        for (int c = 0; c < 8; ++c) red2[wave][lane * 8 + c] = acc[c];
    }
    __syncthreads();
    if (tid < 64) {
        float s = red2[0][tid] + red2[1][tid] + red2[2][tid] + red2[3][tid];
        float ss = s * s;
#pragma unroll
        for (int off = 32; off >= 1; off >>= 1) ss += __shfl_xor(ss, off);
        sout[tid] = s * rsqrtf(ss + 1e-7f);
    }
    __syncthreads();

    // phase B: logits from registers
    const f32x4 o0 = *(const f32x4*)(sout + g * 8);
    const f32x4 o1 = *(const f32x4*)(sout + g * 8 + 4);
#pragma unroll
    for (int it = 0; it < 16; ++it) {
        const bf16x8 v = ur[it];
        float p = o0[0] * (float)v[0] + o0[1] * (float)v[1] +
                  o0[2] * (float)v[2] + o0[3] * (float)v[3] +
                  o1[0] * (float)v[4] + o1[1] * (float)v[5] +
                  o1[2] * (float)v[6] + o1[3] * (float)v[7];
        p += __shfl_xor(p, 1);
        p += __shfl_xor(p, 2);
        p += __shfl_xor(p, 4);
        if (g == 0)
            BLout[((size_t)(b * NCAP + cap)) * IN_CAPS + it * 32 + jr] = p;
    }
}

// ---------------------------------------------------------------------------
// Kernel 5b: generic routing pass (round-5 validated) — mode 2 (final) in the
// main path; modes 0/1/2 in fallback tiers.
// ---------------------------------------------------------------------------
__global__ __launch_bounds__(256) void k_route(const bf16* __restrict__ U,
                                               float* __restrict__ BL,
                                               float* __restrict__ OutC,
                                               int mode) {
    __shared__ float sc[IN_CAPS];
    __shared__ float red2[4][64];
    __shared__ float sout[64];
    const int bi = blockIdx.x;
    const int b = bi >> 4, cap = bi & 15;
    const int tid = threadIdx.x;
    const int lane = tid & 63;
    const int wave = tid >> 6;
    const size_t ubase = (size_t)bi * IN_CAPS * DCAP;

    if (mode == 0) {
        sc[tid] = 0.0625f;
        sc[tid + 256] = 0.0625f;
    } else {
#pragma unroll
        for (int h = 0; h < 2; ++h) {
            const int j = tid + h * 256;
            const float* p = BL + (size_t)b * NCAP * IN_CAPS + j;
            float v[16], mx = -1e30f;
#pragma unroll
            for (int i = 0; i < 16; ++i) {
                v[i] = p[(size_t)i * IN_CAPS];
                mx = fmaxf(mx, v[i]);
            }
            float s = 0.f;
#pragma unroll
            for (int i = 0; i < 16; ++i) s += __expf(v[i] - mx);
            sc[j] = __expf(v[cap] - mx) / s;
        }
    }
    __syncthreads();

    const int g = tid & 7;
    const int jr = tid >> 3;

    float acc[8] = {};
#pragma unroll
    for (int it = 0; it < 16; ++it) {
        const int j = it * 32 + jr;
        const bf16x8 v = *(const bf16x8*)(U + ubase + (size_t)it * 2048 + tid * 8);
        const float cv = sc[j];
#pragma unroll
        for (int c = 0; c < 8; ++c) acc[c] += cv * (float)v[c];
    }
#pragma unroll
    for (int c = 0; c < 8; ++c) {
        acc[c] += __shfl_xor(acc[c], 8);
        acc[c] += __shfl_xor(acc[c], 16);
        acc[c] += __shfl_xor(acc[c], 32);
    }
    if ((lane >> 3) == 0) {
#pragma unroll
        for (int c = 0; c < 8; ++c) red2[wave][lane * 8 + c] = acc[c];
    }
    __syncthreads();

    if (tid < 64) {
        float s = red2[0][tid] + red2[1][tid] + red2[2][tid] + red2[3][tid];
        float ss = s * s;
#pragma unroll
        for (int off = 32; off >= 1; off >>= 1) ss += __shfl_xor(ss, off);
        const float val = s * rsqrtf(ss + 1e-7f);
        sout[tid] = val;
        if (mode == 2) OutC[(size_t)bi * DCAP + tid] = val;
    }
    if (mode == 2) return;
    __syncthreads();

    const f32x4 o0 = *(const f32x4*)(sout + g * 8);
    const f32x4 o1 = *(const f32x4*)(sout + g * 8 + 4);
#pragma unroll
    for (int it = 0; it < 16; ++it) {
        const int j = it * 32 + jr;
        const bf16x8 v = *(const bf16x8*)(U + ubase + (size_t)it * 2048 + tid * 8);
        float p = o0[0] * (float)v[0] + o0[1] * (float)v[1] +
                  o0[2] * (float)v[2] + o0[3] * (float)v[3] +
                  o1[0] * (float)v[4] + o1[1] * (float)v[5] +
                  o1[2] * (float)v[6] + o1[3] * (float)v[7];
        p += __shfl_xor(p, 1);
        p += __shfl_xor(p, 2);
        p += __shfl_xor(p, 4);
        if (g == 0) BL[((size_t)b * NCAP + cap) * IN_CAPS + j] = p;
    }
}

// ---------------------------------------------------------------------------
extern "C" void kernel_launch(void* const* d_in, const int* in_sizes, int n_in,
                              void* d_out, int out_size, void* d_ws, size_t ws_size,
                              hipStream_t stream) {
    const float* X = (const float*)d_in[0]; // [64][512][768] fp32
    const float* W = (const float*)d_in[1]; // [768][1024] fp32
    float* OutC = (float*)d_out;            // [64][16][64] fp32

    const size_t u_bytes = (size_t)BATCH * NCAP * IN_CAPS * DCAP * sizeof(bf16); // 64 MiB
    const size_t xb_bytes = (size_t)GM * GK * sizeof(bf16);                      // 48 MiB
    const size_t wt_bytes = (size_t)GN * GK * sizeof(bf16);                      // 1.5 MiB
    const size_t bl_bytes = (size_t)BATCH * NCAP * IN_CAPS * sizeof(float);      // 2 MiB
    const size_t xsp_bytes = (size_t)1024 * GK * sizeof(float);                  // 3 MiB
    const size_t o1_bytes = (size_t)BATCH * GN * sizeof(float);                  // 256 KiB
    char* ws = (char*)d_ws;

    const size_t need_full = u_bytes + xb_bytes + wt_bytes + bl_bytes + xsp_bytes + o1_bytes;
    const size_t need_async = u_bytes + xb_bytes + wt_bytes + bl_bytes;
    const size_t need_small = u_bytes + wt_bytes + bl_bytes;

    bf16* U = (bf16*)ws;

    if (ws_size >= need_full) {
        bf16* Xb = (bf16*)(ws + u_bytes);
        bf16* Wt = (bf16*)(ws + u_bytes + xb_bytes);
        float* BL = (float*)(ws + u_bytes + xb_bytes + wt_bytes);
        float* XSP = (float*)(ws + u_bytes + xb_bytes + wt_bytes + bl_bytes);
        float* O1 = (float*)(ws + u_bytes + xb_bytes + wt_bytes + bl_bytes + xsp_bytes);
        float* BLtmp = (float*)Xb;  // Xb (48 MiB) is dead after the gemm

        k_prep<<<1024 + 768, 256, 0, stream>>>(X, Xb, XSP, W, Wt);
        k_out1<<<256, 256, 0, stream>>>(XSP, W, O1);
        k_gemm_async<<<2048, 256, 0, stream>>>(Xb, Wt, O1, U, BL);
        // routing iter 0 folded into out1 + gemm epilogue;
        // iter 1 register-staged (BL -> BLtmp); iter 2 reads BLtmp.
        k_route1r<<<BATCH * NCAP, 256, 0, stream>>>(U, BL, BLtmp);
        k_route<<<BATCH * NCAP, 256, 0, stream>>>(U, BLtmp, OutC, 2);
    } else if (ws_size >= need_async) {
        bf16* Xb = (bf16*)(ws + u_bytes);
        bf16* Wt = (bf16*)(ws + u_bytes + xb_bytes);
        float* BL = (float*)(ws + u_bytes + xb_bytes + wt_bytes);
        k_transW<<<dim3(GK / 32, GN / 32), dim3(32, 8), 0, stream>>>(W, Wt);
        k_convX<<<GM * GK / (256 * 8), 256, 0, stream>>>(X, Xb);
        k_gemm_async<<<2048, 256, 0, stream>>>(Xb, Wt, nullptr, U, BL);
        k_route<<<BATCH * NCAP, 256, 0, stream>>>(U, BL, OutC, 0);
        k_route<<<BATCH * NCAP, 256, 0, stream>>>(U, BL, OutC, 1);
        k_route<<<BATCH * NCAP, 256, 0, stream>>>(U, BL, OutC, 2);
    } else if (ws_size >= need_small) {
        bf16* Wt = (bf16*)(ws + u_bytes);
        float* BL = (float*)(ws + u_bytes + wt_bytes);
        k_transW<<<dim3(GK / 32, GN / 32), dim3(32, 8), 0, stream>>>(W, Wt);
        k_gemm_inline<<<dim3(GM / 128, GN / 128), 256, 0, stream>>>(X, Wt, U);
        k_route<<<BATCH * NCAP, 256, 0, stream>>>(U, BL, OutC, 0);
        k_route<<<BATCH * NCAP, 256, 0, stream>>>(U, BL, OutC, 1);
        k_route<<<BATCH * NCAP, 256, 0, stream>>>(U, BL, OutC, 2);
    }
}

// Round 8
// 287.533 us; speedup vs baseline: 1.1273x; 1.1273x over previous
//
#include <hip/hip_runtime.h>
#include <hip/hip_bf16.h>
#include <stdint.h>

// Problem constants
#define BATCH 64
#define IN_CAPS 512          // In (input capsules)
#define NCAP 16              // num_capsule
#define DCAP 64              // dim_capsule
#define GN (NCAP * DCAP)     // 1024
#define GM (BATCH * IN_CAPS) // 32768
#define GK 768               // input feature dim (K)

typedef __bf16 bf16;
typedef __attribute__((ext_vector_type(8))) __bf16 bf16x8;
typedef __attribute__((ext_vector_type(4))) float f32x4;

// async global->LDS 16B copy (wave-uniform LDS base + lane*16)
__device__ inline void async16(const bf16* g, bf16* l) {
    __builtin_amdgcn_global_load_lds(
        (__attribute__((address_space(1))) void*)g,
        (__attribute__((address_space(3))) void*)l, 16, 0, 0);
}

// ---------------------------------------------------------------------------
// Kernel 1: X (fp32) -> bf16 convert + per-b row-sum partials (round-5
// validated).  Register accumulation, single LDS merge at the end.
// ---------------------------------------------------------------------------
__global__ __launch_bounds__(256) void k_convX2(const float* __restrict__ X,
                                                bf16* __restrict__ Xb,
                                                float* __restrict__ XS) {
    __shared__ float ls[GK];
    const int tid = threadIdx.x;
    ls[tid] = 0.f; ls[tid + 256] = 0.f; ls[tid + 512] = 0.f;
    __syncthreads();
    const size_t base = (size_t)blockIdx.x * (32 * GK);
    float acc[3][8] = {};  // static indices only (g = r%3 is compile-time)
#pragma unroll
    for (int r = 0; r < 12; ++r) {
        const int off = r * 2048 + tid * 8;  // 12*2048 = 24576 = 32*768
        const f32x4 a0 = *(const f32x4*)(X + base + off);
        const f32x4 a1 = *(const f32x4*)(X + base + off + 4);
        bf16x8 o;
        o[0] = (bf16)a0[0]; o[1] = (bf16)a0[1]; o[2] = (bf16)a0[2]; o[3] = (bf16)a0[3];
        o[4] = (bf16)a1[0]; o[5] = (bf16)a1[1]; o[6] = (bf16)a1[2]; o[7] = (bf16)a1[3];
        *(bf16x8*)(Xb + base + off) = o;
        const int g = r % 3;  // compile-time within the unrolled body
        acc[g][0] += a0[0]; acc[g][1] += a0[1];
        acc[g][2] += a0[2]; acc[g][3] += a0[3];
        acc[g][4] += a1[0]; acc[g][5] += a1[1];
        acc[g][6] += a1[2]; acc[g][7] += a1[3];
    }
    if (XS != nullptr) {
        // one-time merge: 24 LDS atomics/thread, off the streaming path
#pragma unroll
        for (int g = 0; g < 3; ++g) {
            const int cg = (g == 1) ? 512 : (g == 2) ? 256 : 0;
            const int kb = (tid * 8 + cg) % GK;  // 8-group never straddles row end
#pragma unroll
            for (int j = 0; j < 8; ++j) atomicAdd(&ls[kb + j], acc[g][j]);
        }
        __syncthreads();
        const int bidx = blockIdx.x >> 4;  // 16 blocks of 32 rows per b
        atomicAdd(&XS[(size_t)bidx * GK + tid],       ls[tid]);
        atomicAdd(&XS[(size_t)bidx * GK + tid + 256], ls[tid + 256]);
        atomicAdd(&XS[(size_t)bidx * GK + tid + 512], ls[tid + 512]);
    }
}

// ---------------------------------------------------------------------------
// Kernel 2: transpose W [768][1024] fp32 -> Wt [1024][768] bf16 (K-contig).
// Also zeroes XS (runs before k_convX2 on the stream).  (round-5 validated)
// ---------------------------------------------------------------------------
__global__ void k_transW(const float* __restrict__ W, bf16* __restrict__ Wt,
                         float* __restrict__ XS) {
    __shared__ bf16 t[32][33];
    const int k0 = blockIdx.x * 32;
    const int n0 = blockIdx.y * 32;
    const int tx = threadIdx.x, ty = threadIdx.y;
    if (XS != nullptr) {
        const int gid = (blockIdx.y * gridDim.x + blockIdx.x) * 256 + ty * 32 + tx;
        if (gid < BATCH * GK) XS[gid] = 0.f;
    }
#pragma unroll
    for (int r = 0; r < 4; ++r)
        t[ty + r * 8][tx] = (bf16)W[(size_t)(k0 + ty + r * 8) * GN + n0 + tx];
    __syncthreads();
#pragma unroll
    for (int r = 0; r < 4; ++r)
        Wt[(size_t)(n0 + ty + r * 8) * GK + k0 + tx] = t[tx][ty + r * 8];
}

// ---------------------------------------------------------------------------
// Kernel 3: out1 = squash((1/16) * xsum . W).  (round-5 validated)
// ---------------------------------------------------------------------------
__global__ __launch_bounds__(256) void k_out1(const float* __restrict__ XS,
                                              const float* __restrict__ W,
                                              float* __restrict__ O1) {
    __shared__ float xs[4][GK];      // 12 KiB
    __shared__ float red[4][4][64];  // 4 KiB [bb][kq][k]
    const int cap = blockIdx.x & 15;
    const int bg = blockIdx.x >> 4;
    const int tid = threadIdx.x;
    const int k = tid & 63, kq = tid >> 6;  // kq: kk-quarter (192 each)
#pragma unroll
    for (int bb = 0; bb < 4; ++bb) {
        const size_t b = (size_t)(bg * 4 + bb);
        xs[bb][tid]       = XS[b * GK + tid];
        xs[bb][tid + 256] = XS[b * GK + tid + 256];
        xs[bb][tid + 512] = XS[b * GK + tid + 512];
    }
    __syncthreads();
    float acc4[4] = {0.f, 0.f, 0.f, 0.f};
    const float* wp = W + (size_t)(kq * 192) * GN + cap * 64 + k;
#pragma unroll 4
    for (int kk = 0; kk < 192; ++kk) {
        const float w = wp[(size_t)kk * GN];
        const int kx = kq * 192 + kk;
        acc4[0] += xs[0][kx] * w;
        acc4[1] += xs[1][kx] * w;
        acc4[2] += xs[2][kx] * w;
        acc4[3] += xs[3][kx] * w;
    }
#pragma unroll
    for (int bb = 0; bb < 4; ++bb) red[bb][kq][k] = acc4[bb];
    __syncthreads();
    if (tid < 64) {
#pragma unroll
        for (int bb = 0; bb < 4; ++bb) {
            float s = (red[bb][0][tid] + red[bb][1][tid] +
                       red[bb][2][tid] + red[bb][3][tid]) * 0.0625f;
            float ss = s * s;
#pragma unroll
            for (int off = 32; off >= 1; off >>= 1) ss += __shfl_xor(ss, off);
            O1[((size_t)(bg * 4 + bb) * NCAP + cap) * DCAP + tid] =
                s * rsqrtf(ss + 1e-7f);
        }
    }
}

// ---------------------------------------------------------------------------
// Kernel 4: MFMA GEMM — round-0 validated staging (address-ordered lanes;
// DO NOT trade intra-wave address order for LDS conflict purity — rounds 3-4
// lost 40 µs that way) + XCD-bijective block swizzle (ROUND-7 VALIDATED:
// FETCH 80 -> 42.7 MB, dur 91 -> 83 µs).  1-D grid 2048 (2048%8==0 ->
// bijective); XCD x gets m-tiles [32x,32x+32), n fastest -> A-panel L2-hot
// across its 8 consumers.
// Epilogue: U store + BL1 = <out1, u_j> from fp32 accumulators (validated).
// ---------------------------------------------------------------------------
__global__ __launch_bounds__(256) void k_gemm_async(const bf16* __restrict__ Xb,
                                                    const bf16* __restrict__ Wt,
                                                    const float* __restrict__ O1,
                                                    bf16* __restrict__ U,
                                                    float* __restrict__ BL) {
    __shared__ bf16 sA[128 * 32];
    __shared__ bf16 sB[128 * 32];

    const int tid = threadIdx.x;
    const int lane = tid & 63;
    const int wave = tid >> 6;
    const int wm = wave >> 1, wn = wave & 1;
    // XCD swizzle: bid%8 = XCD; give XCD x a contiguous m-range, n fastest.
    const int bid = blockIdx.x;
    const int swz = (bid & 7) * 256 + (bid >> 3);
    const int m0 = (swz >> 3) * 128;
    const int n0 = (swz & 7) * 128;

    const int c0 = wave * 2, c1 = wave * 2 + 1;
    const int rl = lane >> 2, cl = (lane & 3) * 8;
    const bf16* gA0 = Xb + (size_t)(m0 + c0 * 16 + rl) * GK + cl;
    const bf16* gA1 = Xb + (size_t)(m0 + c1 * 16 + rl) * GK + cl;
    const bf16* gB0 = Wt + (size_t)(n0 + c0 * 16 + rl) * GK + cl;
    const bf16* gB1 = Wt + (size_t)(n0 + c1 * 16 + rl) * GK + cl;
    bf16* lA0 = sA + c0 * 512;
    bf16* lA1 = sA + c1 * 512;
    bf16* lB0 = sB + c0 * 512;
    bf16* lB1 = sB + c1 * 512;

    f32x4 acc[4][4] = {};
    const int fr = lane & 15;
    const int fq = lane >> 4;

    for (int kt = 0; kt < GK / 32; ++kt) {
        __syncthreads();
        async16(gA0, lA0);
        async16(gA1, lA1);
        async16(gB0, lB0);
        async16(gB1, lB1);
        gA0 += 32; gA1 += 32; gB0 += 32; gB1 += 32;
        __syncthreads();

        bf16x8 af[4], bfr[4];
#pragma unroll
        for (int mi = 0; mi < 4; ++mi)
            af[mi] = *(const bf16x8*)(sA + (wm * 64 + mi * 16 + fr) * 32 + fq * 8);
#pragma unroll
        for (int ni = 0; ni < 4; ++ni)
            bfr[ni] = *(const bf16x8*)(sB + (wn * 64 + ni * 16 + fr) * 32 + fq * 8);
#pragma unroll
        for (int mi = 0; mi < 4; ++mi)
#pragma unroll
            for (int ni = 0; ni < 4; ++ni)
                acc[mi][ni] = __builtin_amdgcn_mfma_f32_16x16x32_bf16(
                    af[mi], bfr[ni], acc[mi][ni], 0, 0, 0);
    }

    // --- epilogue: U store (validated mapping) ---
#pragma unroll
    for (int mi = 0; mi < 4; ++mi) {
#pragma unroll
        for (int ni = 0; ni < 4; ++ni) {
#pragma unroll
            for (int r = 0; r < 4; ++r) {
                const int m = m0 + wm * 64 + mi * 16 + fq * 4 + r;
                const int n = n0 + wn * 64 + ni * 16 + fr;
                const int bb = m >> 9, j = m & 511;
                const int ci = n >> 6, k = n & 63;
                U[(((size_t)(bb * NCAP + ci)) * IN_CAPS + j) * DCAP + k] =
                    (bf16)acc[mi][ni][r];
            }
        }
    }

    // --- epilogue: BL1[b,cap,j] = <out1[b,cap,:], u[b,cap,j,:]> (validated) ---
    if (O1 != nullptr) {
        const int b = m0 >> 9;
        const int cap = (n0 >> 6) + wn;
        float o1v[4];
#pragma unroll
        for (int ni = 0; ni < 4; ++ni)
            o1v[ni] = O1[(size_t)b * GN + n0 + wn * 64 + ni * 16 + fr];
#pragma unroll
        for (int mi = 0; mi < 4; ++mi) {
#pragma unroll
            for (int r = 0; r < 4; ++r) {
                float p = o1v[0] * acc[mi][0][r] + o1v[1] * acc[mi][1][r] +
                          o1v[2] * acc[mi][2][r] + o1v[3] * acc[mi][3][r];
                p += __shfl_xor(p, 1);
                p += __shfl_xor(p, 2);
                p += __shfl_xor(p, 4);
                p += __shfl_xor(p, 8);
                if (fr == 0) {
                    const int j = (m0 & 511) + wm * 64 + mi * 16 + fq * 4 + r;
                    BL[((size_t)(b * NCAP + cap)) * IN_CAPS + j] = p;
                }
            }
        }
    }
}

// ---------------------------------------------------------------------------
// Kernel 4b: fallback GEMM (validated, inline conversion).
// ---------------------------------------------------------------------------
__global__ __launch_bounds__(256) void k_gemm_inline(const float* __restrict__ X,
                                                     const bf16* __restrict__ Wt,
                                                     bf16* __restrict__ U) {
    __shared__ bf16 sA[128 * 32];
    __shared__ bf16 sB[128 * 32];
    const int tid = threadIdx.x;
    const int lane = tid & 63;
    const int wave = tid >> 6;
    const int wm = wave >> 1, wn = wave & 1;
    const int m0 = blockIdx.x * 128;
    const int n0 = blockIdx.y * 128;
    const int srow = tid >> 2;
    const int scol = (tid & 3) * 8;
    f32x4 acc[4][4] = {};
    const int fr = lane & 15;
    const int fq = lane >> 4;
    for (int kt = 0; kt < GK / 32; ++kt) {
        const int kb = kt * 32;
        bf16x8 a0, a1, b0, b1;
        {
            const float* p = X + (size_t)(m0 + srow) * GK + kb + scol;
            const f32x4 x0 = *(const f32x4*)p, x1 = *(const f32x4*)(p + 4);
            const float* q = X + (size_t)(m0 + srow + 64) * GK + kb + scol;
            const f32x4 y0 = *(const f32x4*)q, y1 = *(const f32x4*)(q + 4);
#pragma unroll
            for (int c = 0; c < 4; ++c) {
                a0[c] = (bf16)x0[c]; a0[c + 4] = (bf16)x1[c];
                a1[c] = (bf16)y0[c]; a1[c + 4] = (bf16)y1[c];
            }
        }
        b0 = *(const bf16x8*)(Wt + (size_t)(n0 + srow) * GK + kb + scol);
        b1 = *(const bf16x8*)(Wt + (size_t)(n0 + srow + 64) * GK + kb + scol);
        __syncthreads();
        *(bf16x8*)(sA + srow * 32 + scol) = a0;
        *(bf16x8*)(sA + (srow + 64) * 32 + scol) = a1;
        *(bf16x8*)(sB + srow * 32 + scol) = b0;
        *(bf16x8*)(sB + (srow + 64) * 32 + scol) = b1;
        __syncthreads();
        bf16x8 af[4], bfr[4];
#pragma unroll
        for (int mi = 0; mi < 4; ++mi)
            af[mi] = *(const bf16x8*)(sA + (wm * 64 + mi * 16 + fr) * 32 + fq * 8);
#pragma unroll
        for (int ni = 0; ni < 4; ++ni)
            bfr[ni] = *(const bf16x8*)(sB + (wn * 64 + ni * 16 + fr) * 32 + fq * 8);
#pragma unroll
        for (int mi = 0; mi < 4; ++mi)
#pragma unroll
            for (int ni = 0; ni < 4; ++ni)
                acc[mi][ni] = __builtin_amdgcn_mfma_f32_16x16x32_bf16(
                    af[mi], bfr[ni], acc[mi][ni], 0, 0, 0);
    }
#pragma unroll
    for (int mi = 0; mi < 4; ++mi) {
#pragma unroll
        for (int ni = 0; ni < 4; ++ni) {
#pragma unroll
            for (int r = 0; r < 4; ++r) {
                const int m = m0 + wm * 64 + mi * 16 + fq * 4 + r;
                const int n = n0 + wn * 64 + ni * 16 + fr;
                const int bb = m >> 9, j = m & 511;
                const int ci = n >> 6, k = n & 63;
                U[(((size_t)(bb * NCAP + ci)) * IN_CAPS + j) * DCAP + k] =
                    (bf16)acc[mi][ni][r];
            }
        }
    }
}

// ---------------------------------------------------------------------------
// Kernel 5: routing pass (round-5 validated structure) with split BLin/BLout
// (mode-1 writes a separate buffer -> no cross-block logits race).
//   mode 0: c = 1/16, write logits to BLout
//   mode 1: c = softmax(BLin over caps), write logits to BLout
//   mode 2: c = softmax(BLin), write OutC, no logits
// ---------------------------------------------------------------------------
__global__ __launch_bounds__(256) void k_route(const bf16* __restrict__ U,
                                               const float* __restrict__ BLin,
                                               float* __restrict__ BLout,
                                               float* __restrict__ OutC,
                                               int mode) {
    __shared__ float sc[IN_CAPS];  // 2 KiB
    __shared__ float red2[4][64];  // 1 KiB
    __shared__ float sout[64];     // 256 B
    const int bi = blockIdx.x;
    const int b = bi >> 4, cap = bi & 15;
    const int tid = threadIdx.x;
    const int lane = tid & 63;
    const int wave = tid >> 6;
    const size_t ubase = (size_t)bi * IN_CAPS * DCAP;

    if (mode == 0) {
        sc[tid] = 0.0625f;
        sc[tid + 256] = 0.0625f;
    } else {
#pragma unroll
        for (int h = 0; h < 2; ++h) {
            const int j = tid + h * 256;
            const float* p = BLin + (size_t)b * NCAP * IN_CAPS + j;
            float v[16], mx = -1e30f;
#pragma unroll
            for (int i = 0; i < 16; ++i) {
                v[i] = p[(size_t)i * IN_CAPS];
                mx = fmaxf(mx, v[i]);
            }
            float s = 0.f;
#pragma unroll
            for (int i = 0; i < 16; ++i) s += __expf(v[i] - mx);
            sc[j] = __expf(v[cap] - mx) / s;
        }
    }
    __syncthreads();

    const int g = tid & 7;   // k-octet
    const int jr = tid >> 3; // j-row group 0..31

    float acc[8] = {};
#pragma unroll
    for (int it = 0; it < 16; ++it) {
        const int j = it * 32 + jr;
        const bf16x8 v = *(const bf16x8*)(U + ubase + (size_t)it * 2048 + tid * 8);
        const float cv = sc[j];
#pragma unroll
        for (int c = 0; c < 8; ++c) acc[c] += cv * (float)v[c];
    }
#pragma unroll
    for (int c = 0; c < 8; ++c) {
        acc[c] += __shfl_xor(acc[c], 8);
        acc[c] += __shfl_xor(acc[c], 16);
        acc[c] += __shfl_xor(acc[c], 32);
    }
    if ((lane >> 3) == 0) {
#pragma unroll
        for (int c = 0; c < 8; ++c) red2[wave][lane * 8 + c] = acc[c];
    }
    __syncthreads();

    if (tid < 64) {
        float s = red2[0][tid] + red2[1][tid] + red2[2][tid] + red2[3][tid];
        float ss = s * s;
#pragma unroll
        for (int off = 32; off >= 1; off >>= 1) ss += __shfl_xor(ss, off);
        const float val = s * rsqrtf(ss + 1e-7f);
        sout[tid] = val;
        if (mode == 2) OutC[(size_t)bi * DCAP + tid] = val;
    }
    if (mode == 2) return;
    __syncthreads();

    const f32x4 o0 = *(const f32x4*)(sout + g * 8);
    const f32x4 o1 = *(const f32x4*)(sout + g * 8 + 4);
#pragma unroll
    for (int it = 0; it < 16; ++it) {
        const int j = it * 32 + jr;
        const bf16x8 v = *(const bf16x8*)(U + ubase + (size_t)it * 2048 + tid * 8);
        float p = o0[0] * (float)v[0] + o0[1] * (float)v[1] +
                  o0[2] * (float)v[2] + o0[3] * (float)v[3] +
                  o1[0] * (float)v[4] + o1[1] * (float)v[5] +
                  o1[2] * (float)v[6] + o1[3] * (float)v[7];
        p += __shfl_xor(p, 1);
        p += __shfl_xor(p, 2);
        p += __shfl_xor(p, 4);
        if (g == 0) BLout[((size_t)(b * NCAP + cap)) * IN_CAPS + j] = p;
    }
}

// ---------------------------------------------------------------------------
extern "C" void kernel_launch(void* const* d_in, const int* in_sizes, int n_in,
                              void* d_out, int out_size, void* d_ws, size_t ws_size,
                              hipStream_t stream) {
    const float* X = (const float*)d_in[0]; // [64][512][768] fp32
    const float* W = (const float*)d_in[1]; // [768][1024] fp32
    float* OutC = (float*)d_out;            // [64][16][64] fp32

    const size_t u_bytes = (size_t)BATCH * NCAP * IN_CAPS * DCAP * sizeof(bf16); // 64 MiB
    const size_t xb_bytes = (size_t)GM * GK * sizeof(bf16);                      // 48 MiB
    const size_t wt_bytes = (size_t)GN * GK * sizeof(bf16);                      // 1.5 MiB
    const size_t bl_bytes = (size_t)BATCH * NCAP * IN_CAPS * sizeof(float);      // 2 MiB
    const size_t xs_bytes = (size_t)BATCH * GK * sizeof(float);                  // 192 KiB
    const size_t o1_bytes = (size_t)BATCH * GN * sizeof(float);                  // 256 KiB
    char* ws = (char*)d_ws;

    const size_t need_full = u_bytes + xb_bytes + wt_bytes + bl_bytes + xs_bytes + o1_bytes;
    const size_t need_async = u_bytes + xb_bytes + wt_bytes + bl_bytes;
    const size_t need_small = u_bytes + wt_bytes + bl_bytes;

    bf16* U = (bf16*)ws;

    if (ws_size >= need_full) {
        bf16* Xb = (bf16*)(ws + u_bytes);
        bf16* Wt = (bf16*)(ws + u_bytes + xb_bytes);
        float* BL = (float*)(ws + u_bytes + xb_bytes + wt_bytes);
        float* XS = (float*)(ws + u_bytes + xb_bytes + wt_bytes + bl_bytes);
        float* O1 = (float*)(ws + u_bytes + xb_bytes + wt_bytes + bl_bytes + xs_bytes);
        float* BLtmp = (float*)Xb;  // Xb (48 MiB) is dead after the gemm

        // transW FIRST: zeroes XS before convX2's atomics (stream-ordered)
        k_transW<<<dim3(GK / 32, GN / 32), dim3(32, 8), 0, stream>>>(W, Wt, XS);
        k_convX2<<<GM / 32, 256, 0, stream>>>(X, Xb, XS);
        k_out1<<<256, 256, 0, stream>>>(XS, W, O1);
        k_gemm_async<<<2048, 256, 0, stream>>>(Xb, Wt, O1, U, BL);
        // routing iter 0 folded into out1 + gemm epilogue;
        // iter 1: BL -> BLtmp; iter 2: BLtmp -> OutC (no same-buffer race)
        k_route<<<BATCH * NCAP, 256, 0, stream>>>(U, BL, BLtmp, OutC, 1);
        k_route<<<BATCH * NCAP, 256, 0, stream>>>(U, BLtmp, nullptr, OutC, 2);
    } else if (ws_size >= need_async) {
        bf16* Xb = (bf16*)(ws + u_bytes);
        bf16* Wt = (bf16*)(ws + u_bytes + xb_bytes);
        float* BL = (float*)(ws + u_bytes + xb_bytes + wt_bytes);
        float* BLtmp = (float*)Xb;  // dead after gemm
        k_transW<<<dim3(GK / 32, GN / 32), dim3(32, 8), 0, stream>>>(W, Wt, nullptr);
        k_convX2<<<GM / 32, 256, 0, stream>>>(X, Xb, nullptr);
        k_gemm_async<<<2048, 256, 0, stream>>>(Xb, Wt, nullptr, U, BL);
        k_route<<<BATCH * NCAP, 256, 0, stream>>>(U, nullptr, BL, OutC, 0);
        k_route<<<BATCH * NCAP, 256, 0, stream>>>(U, BL, BLtmp, OutC, 1);
        k_route<<<BATCH * NCAP, 256, 0, stream>>>(U, BLtmp, nullptr, OutC, 2);
    } else if (ws_size >= need_small) {
        bf16* Wt = (bf16*)(ws + u_bytes);
        float* BL = (float*)(ws + u_bytes + wt_bytes);
        k_transW<<<dim3(GK / 32, GN / 32), dim3(32, 8), 0, stream>>>(W, Wt, nullptr);
        k_gemm_inline<<<dim3(GM / 128, GN / 128), 256, 0, stream>>>(X, Wt, U);
        // no scratch buffer available: same-buffer logits (historical behavior)
        k_route<<<BATCH * NCAP, 256, 0, stream>>>(U, BL, BL, OutC, 0);
        k_route<<<BATCH * NCAP, 256, 0, stream>>>(U, BL, BL, OutC, 1);
        k_route<<<BATCH * NCAP, 256, 0, stream>>>(U, BL, BL, OutC, 2);
    }
}